// Round 2
// baseline (1186.919 us; speedup 1.0000x reference)
//
#include <hip/hip_runtime.h>
#include <hip/hip_bf16.h>
#include <math.h>

// ---------------- types ----------------
typedef unsigned int  uint4v __attribute__((ext_vector_type(4)));
typedef float         f32x4  __attribute__((ext_vector_type(4)));
typedef __bf16        bf16x8 __attribute__((ext_vector_type(8)));
typedef unsigned short u16x8 __attribute__((ext_vector_type(8)));

#define D_MODEL 512
#define SEQ     2048
#define BTOK    4096   // B * SEQ
#define HIDE    2048
#define NHEAD   8
#define HD      64

static __device__ __forceinline__ unsigned short f2bf(float f) {
  union { float f; unsigned u; } v; v.f = f;
  unsigned r = v.u + 0x7FFFu + ((v.u >> 16) & 1u);   // RNE
  return (unsigned short)(r >> 16);
}
static __device__ __forceinline__ float bf2f(unsigned short b) {
  union { unsigned u; float f; } v; v.u = ((unsigned)b) << 16;
  return v.f;
}
static __device__ __forceinline__ bf16x8 ldb8(const unsigned short* p) {
  return __builtin_bit_cast(bf16x8, *(const uint4v*)p);
}
static __device__ __forceinline__ f32x4 mfma16(bf16x8 a, bf16x8 b, f32x4 c) {
  return __builtin_amdgcn_mfma_f32_16x16x32_bf16(a, b, c, 0, 0, 0);
}

// ---------------- RMSNorm: fp32 in -> bf16 out ----------------
__global__ __launch_bounds__(64) void rmsnorm_k(const float* __restrict__ x,
                                                const float* __restrict__ w,
                                                unsigned short* __restrict__ out) {
  int row  = blockIdx.x;
  int lane = threadIdx.x;
  const float* xr = x + (size_t)row * D_MODEL;
  f32x4 v0 = *(const f32x4*)(xr + lane * 8);
  f32x4 v1 = *(const f32x4*)(xr + lane * 8 + 4);
  float ss = v0.x*v0.x + v0.y*v0.y + v0.z*v0.z + v0.w*v0.w
           + v1.x*v1.x + v1.y*v1.y + v1.z*v1.z + v1.w*v1.w;
  #pragma unroll
  for (int m = 1; m < 64; m <<= 1) ss += __shfl_xor(ss, m, 64);
  float inv = 1.0f / (sqrtf(ss * (1.0f / D_MODEL)) + 1e-6f);
  f32x4 w0 = *(const f32x4*)(w + lane * 8);
  f32x4 w1 = *(const f32x4*)(w + lane * 8 + 4);
  u16x8 o;
  o[0] = f2bf(v0.x * w0.x * inv); o[1] = f2bf(v0.y * w0.y * inv);
  o[2] = f2bf(v0.z * w0.z * inv); o[3] = f2bf(v0.w * w0.w * inv);
  o[4] = f2bf(v1.x * w1.x * inv); o[5] = f2bf(v1.y * w1.y * inv);
  o[6] = f2bf(v1.z * w1.z * inv); o[7] = f2bf(v1.w * w1.w * inv);
  *(u16x8*)(out + (size_t)row * D_MODEL + lane * 8) = o;
}

// ---------------- GEMM: C = A(bf16, MxK) @ B(f32 weights, KxN) + bias, epilogues ----
// tile 64x64, BK=64, 4 waves (each wave: 16 rows x 64 cols), 16x16x32 MFMA
#define EPI_BF16  0
#define EPI_SILU  1
#define EPI_MUL   2
#define EPI_RESID 3

template<int EPI>
__global__ __launch_bounds__(256) void gemm_k(
    const unsigned short* __restrict__ A,
    const float* __restrict__ B,
    const float* __restrict__ bias,
    void* __restrict__ Cout,
    const unsigned short* __restrict__ gate,
    int M, int N, int K)
{
  __shared__ __attribute__((aligned(16))) unsigned short A_lds[64][72];      // +8 pad
  __shared__ __attribute__((aligned(16))) unsigned short B_swz[8 * 64 * 8];  // [k/8][n][k%8]
  int tid  = threadIdx.x;
  int lane = tid & 63, wave = tid >> 6;
  int g = lane >> 4, c = lane & 15;
  int m0 = blockIdx.y * 64, n0 = blockIdx.x * 64;
  int ar = tid >> 2, ablk = tid & 3;   // staging: row 0..63, 16-col block 0..3

  f32x4 acc[4] = {};

  for (int kt = 0; kt < K; kt += 64) {
    // stage A (bf16): 64x64
    {
      const uint4v* src = (const uint4v*)(A + (size_t)(m0 + ar) * K + kt + ablk * 16);
      uint4v a0 = src[0], a1 = src[1];
      *(uint4v*)&A_lds[ar][ablk * 16]     = a0;
      *(uint4v*)&A_lds[ar][ablk * 16 + 8] = a1;
    }
    // stage B (f32 -> bf16, swizzled [k/8][n][k%8])
    {
      const float* src = B + (size_t)(kt + ar) * N + n0 + ablk * 16;
      f32x4 b0 = *(const f32x4*)(src);
      f32x4 b1 = *(const f32x4*)(src + 4);
      f32x4 b2 = *(const f32x4*)(src + 8);
      f32x4 b3 = *(const f32x4*)(src + 12);
      unsigned short* dst = &B_swz[((ar >> 3) * 64) * 8 + (ar & 7)];
      int nb = ablk * 16;
      dst[(nb + 0) * 8] = f2bf(b0.x); dst[(nb + 1) * 8] = f2bf(b0.y);
      dst[(nb + 2) * 8] = f2bf(b0.z); dst[(nb + 3) * 8] = f2bf(b0.w);
      dst[(nb + 4) * 8] = f2bf(b1.x); dst[(nb + 5) * 8] = f2bf(b1.y);
      dst[(nb + 6) * 8] = f2bf(b1.z); dst[(nb + 7) * 8] = f2bf(b1.w);
      dst[(nb + 8) * 8] = f2bf(b2.x); dst[(nb + 9) * 8] = f2bf(b2.y);
      dst[(nb +10) * 8] = f2bf(b2.z); dst[(nb +11) * 8] = f2bf(b2.w);
      dst[(nb +12) * 8] = f2bf(b3.x); dst[(nb +13) * 8] = f2bf(b3.y);
      dst[(nb +14) * 8] = f2bf(b3.z); dst[(nb +15) * 8] = f2bf(b3.w);
    }
    __syncthreads();
    #pragma unroll
    for (int ks = 0; ks < 2; ++ks) {
      bf16x8 af = ldb8(&A_lds[wave * 16 + c][ks * 32 + g * 8]);
      int kb = ks * 4 + g;
      #pragma unroll
      for (int nb2 = 0; nb2 < 4; ++nb2) {
        bf16x8 bfr = ldb8(&B_swz[(kb * 64 + nb2 * 16 + c) * 8]);
        acc[nb2] = mfma16(af, bfr, acc[nb2]);
      }
    }
    __syncthreads();
  }

  // epilogue: lane holds C[m0+wave*16+g*4+i][n0+nb*16+c]
  #pragma unroll
  for (int nb2 = 0; nb2 < 4; ++nb2) {
    int n = n0 + nb2 * 16 + c;
    float bn = bias[n];
    #pragma unroll
    for (int i = 0; i < 4; ++i) {
      int m = m0 + wave * 16 + g * 4 + i;
      size_t idx = (size_t)m * N + n;
      float v = acc[nb2][i] + bn;
      if (EPI == EPI_BF16) {
        ((unsigned short*)Cout)[idx] = f2bf(v);
      } else if (EPI == EPI_SILU) {
        float s = v / (1.0f + __expf(-v));
        ((unsigned short*)Cout)[idx] = f2bf(s);
      } else if (EPI == EPI_MUL) {
        float t = v * bf2f(gate[idx]);
        ((unsigned short*)Cout)[idx] = f2bf(t);
      } else {
        float* O = (float*)Cout;
        O[idx] = v + O[idx];
      }
    }
  }
}

// ---------------- Flash attention: 1 wave per 16 q-rows, kv tiles of 32 ----
__global__ __launch_bounds__(64) void attn_k(const unsigned short* __restrict__ Q,
                                             const unsigned short* __restrict__ Kt,
                                             const unsigned short* __restrict__ Vt,
                                             unsigned short* __restrict__ O)
{
  __shared__ __attribute__((aligned(16))) unsigned short P_lds[16 * 32];
  __shared__ __attribute__((aligned(16))) unsigned short V_swz[4 * 64 * 8]; // [k/8][d][k%8]
  int lane = threadIdx.x;
  int g = lane >> 4, c = lane & 15;
  int q0 = blockIdx.x * 16;
  int bh = blockIdx.y;
  size_t base = ((size_t)(bh >> 3) * SEQ) * D_MODEL + (size_t)(bh & 7) * HD;

  // Q fragments (rows q0..q0+15, d split in two 32-chunks)
  bf16x8 qf0 = ldb8(Q + base + (size_t)(q0 + c) * D_MODEL + g * 8);
  bf16x8 qf1 = ldb8(Q + base + (size_t)(q0 + c) * D_MODEL + 32 + g * 8);

  float m_i[4], s_i[4];
  f32x4 oacc[4] = {};
  #pragma unroll
  for (int i = 0; i < 4; ++i) { m_i[i] = -3e38f; s_i[i] = 0.0f; }

  int ntiles = (q0 + 16 + 31) >> 5;
  for (int kt = 0; kt < ntiles; ++kt) {
    int kbase = kt * 32;
    // stage V tile 32x64 swizzled
    {
      int kl = lane >> 1;
      int d0 = (lane & 1) * 32;
      const uint4v* vs = (const uint4v*)(Vt + base + (size_t)(kbase + kl) * D_MODEL + d0);
      uint4v t0 = vs[0], t1 = vs[1], t2 = vs[2], t3 = vs[3];
      unsigned short tmp[32];
      *(uint4v*)&tmp[0]  = t0; *(uint4v*)&tmp[8]  = t1;
      *(uint4v*)&tmp[16] = t2; *(uint4v*)&tmp[24] = t3;
      unsigned short* dst = &V_swz[((kl >> 3) * 64) * 8 + (kl & 7)];
      #pragma unroll
      for (int j = 0; j < 32; ++j) dst[(d0 + j) * 8] = tmp[j];
    }
    // scores: two 16-key halves
    f32x4 sc[2];
    #pragma unroll
    for (int hh = 0; hh < 2; ++hh) {
      const unsigned short* kr = Kt + base + (size_t)(kbase + hh * 16 + c) * D_MODEL;
      bf16x8 kf0 = ldb8(kr + g * 8);
      bf16x8 kf1 = ldb8(kr + 32 + g * 8);
      f32x4 z = {};
      z = mfma16(qf0, kf0, z);
      z = mfma16(qf1, kf1, z);
      sc[hh] = z;
    }
    // mask + scale + row max
    float mt[4];
    #pragma unroll
    for (int i = 0; i < 4; ++i) {
      int qrow = q0 + g * 4 + i;
      float a0 = (kbase + c      <= qrow) ? sc[0][i] * 0.125f : -3e38f;
      float a1 = (kbase + 16 + c <= qrow) ? sc[1][i] * 0.125f : -3e38f;
      sc[0][i] = a0; sc[1][i] = a1;
      mt[i] = fmaxf(a0, a1);
    }
    #pragma unroll
    for (int mm = 1; mm < 16; mm <<= 1) {
      #pragma unroll
      for (int i = 0; i < 4; ++i) mt[i] = fmaxf(mt[i], __shfl_xor(mt[i], mm, 64));
    }
    // online softmax update + write P
    float rs[4];
    #pragma unroll
    for (int i = 0; i < 4; ++i) {
      float mnew  = fmaxf(m_i[i], mt[i]);
      float scale = __expf(m_i[i] - mnew);
      m_i[i] = mnew;
      float p0 = __expf(sc[0][i] - mnew);
      float p1 = __expf(sc[1][i] - mnew);
      rs[i] = p0 + p1;
      s_i[i] *= scale;
      #pragma unroll
      for (int nb = 0; nb < 4; ++nb) oacc[nb][i] *= scale;
      P_lds[(g * 4 + i) * 32 + c]      = f2bf(p0);
      P_lds[(g * 4 + i) * 32 + 16 + c] = f2bf(p1);
    }
    #pragma unroll
    for (int mm = 1; mm < 16; mm <<= 1) {
      #pragma unroll
      for (int i = 0; i < 4; ++i) rs[i] += __shfl_xor(rs[i], mm, 64);
    }
    #pragma unroll
    for (int i = 0; i < 4; ++i) s_i[i] += rs[i];
    __syncthreads();
    // P @ V
    bf16x8 pa = ldb8(&P_lds[c * 32 + g * 8]);
    #pragma unroll
    for (int nb = 0; nb < 4; ++nb) {
      bf16x8 vf = ldb8(&V_swz[(g * 64 + nb * 16 + c) * 8]);
      oacc[nb] = mfma16(pa, vf, oacc[nb]);
    }
    __syncthreads();
  }
  float inv[4];
  #pragma unroll
  for (int i = 0; i < 4; ++i) inv[i] = 1.0f / s_i[i];
  #pragma unroll
  for (int nb = 0; nb < 4; ++nb)
    #pragma unroll
    for (int i = 0; i < 4; ++i)
      O[base + (size_t)(q0 + g * 4 + i) * D_MODEL + nb * 16 + c] = f2bf(oacc[nb][i] * inv[i]);
}

// ---------------- launch ----------------
extern "C" void kernel_launch(void* const* d_in, const int* in_sizes, int n_in,
                              void* d_out, int out_size, void* d_ws, size_t ws_size,
                              hipStream_t stream) {
  (void)in_sizes; (void)n_in; (void)out_size; (void)ws_size;
  const float* x   = (const float*)d_in[0];
  const float* qw  = (const float*)d_in[1];
  const float* qb  = (const float*)d_in[2];
  const float* kw  = (const float*)d_in[3];
  const float* kbi = (const float*)d_in[4];
  const float* vw  = (const float*)d_in[5];
  const float* vb  = (const float*)d_in[6];
  const float* ow  = (const float*)d_in[7];
  const float* ob  = (const float*)d_in[8];
  const float* w0  = (const float*)d_in[9];
  const float* b0  = (const float*)d_in[10];
  const float* w1  = (const float*)d_in[11];
  const float* b1  = (const float*)d_in[12];
  const float* w2  = (const float*)d_in[13];
  const float* b2  = (const float*)d_in[14];
  const float* anw = (const float*)d_in[15];
  const float* fnw = (const float*)d_in[16];

  char* ws = (char*)d_ws;
  float*          h    = (float*)ws;                              // 8 MB fp32 residual
  unsigned short* xn   = (unsigned short*)(ws + (8u  << 20));     // 4 MB
  unsigned short* q    = (unsigned short*)(ws + (12u << 20));     // 4 MB
  unsigned short* k    = (unsigned short*)(ws + (16u << 20));     // 4 MB
  unsigned short* v    = (unsigned short*)(ws + (20u << 20));     // 4 MB
  unsigned short* ao   = (unsigned short*)(ws + (24u << 20));     // 4 MB
  unsigned short* gate = (unsigned short*)(ws + (28u << 20));     // 16 MB (silu; then act in-place)

  hipMemcpyAsync(h, x, (size_t)BTOK * D_MODEL * sizeof(float),
                 hipMemcpyDeviceToDevice, stream);

  for (int l = 0; l < 4; ++l) {
    size_t wo  = (size_t)l * D_MODEL * D_MODEL;
    size_t bo  = (size_t)l * D_MODEL;
    size_t w01 = (size_t)l * D_MODEL * HIDE;
    size_t bho = (size_t)l * HIDE;

    rmsnorm_k<<<BTOK, 64, 0, stream>>>(h, anw + bo, xn);
    gemm_k<EPI_BF16><<<dim3(8, 64), 256, 0, stream>>>(xn, qw + wo, qb + bo, q, nullptr, BTOK, D_MODEL, D_MODEL);
    gemm_k<EPI_BF16><<<dim3(8, 64), 256, 0, stream>>>(xn, kw + wo, kbi + bo, k, nullptr, BTOK, D_MODEL, D_MODEL);
    gemm_k<EPI_BF16><<<dim3(8, 64), 256, 0, stream>>>(xn, vw + wo, vb + bo, v, nullptr, BTOK, D_MODEL, D_MODEL);
    attn_k<<<dim3(SEQ / 16, 16), 64, 0, stream>>>(q, k, v, ao);
    gemm_k<EPI_RESID><<<dim3(8, 64), 256, 0, stream>>>(ao, ow + wo, ob + bo, h, nullptr, BTOK, D_MODEL, D_MODEL);

    rmsnorm_k<<<BTOK, 64, 0, stream>>>(h, fnw + bo, xn);
    gemm_k<EPI_SILU><<<dim3(32, 64), 256, 0, stream>>>(xn, w1 + w01, b1 + bho, gate, nullptr, BTOK, HIDE, D_MODEL);
    gemm_k<EPI_MUL><<<dim3(32, 64), 256, 0, stream>>>(xn, w0 + w01, b0 + bho, gate, gate, BTOK, HIDE, D_MODEL);
    gemm_k<EPI_RESID><<<dim3(8, 64), 256, 0, stream>>>(gate, w2 + (size_t)l * HIDE * D_MODEL, b2 + bo, h, nullptr, BTOK, D_MODEL, HIDE);
  }
  // final output: reference dtype is float32 -> copy fp32 residual straight out
  hipMemcpyAsync(d_out, h, (size_t)BTOK * D_MODEL * sizeof(float),
                 hipMemcpyDeviceToDevice, stream);
}